// Round 8
// baseline (74.800 us; speedup 1.0000x reference)
//
#include <hip/hip_runtime.h>
#include <math.h>

namespace {
constexpr int Bn = 4, Cn = 3, Hn = 96, Wn = 96;
constexpr int HWn = Hn * Wn;          // 9216
constexpr int NP  = Bn * Cn;          // 12 (batch,class) pairs
constexpr int NBANDS = 3;             // 32-row bands; band == column-mask word index
constexpr int NBLK1 = Bn * NBANDS;    // 12 blocks in K1
constexpr int SENT = 62500;           // "no boundary in column" d^2 (> 9025+9025)

// ws layout in 4-byte words (~71 KB total).
// flags: [B][HW] bytes at word offset 0. Byte = pc(2b) | label(2b) | bda(1b) | bdb(1b)
constexpr int FLAG_WORDS = Bn * HWn / 4;          // 9216
constexpr int CNT_OFF  = FLAG_WORDS;              // [12 blocks][8]: na[c]=slot c, nb[c]=slot 3+c
constexpr int SUM_OFF  = ((CNT_OFF + NBLK1 * 8 + 15) / 16) * 16;  // line-aligned atomics
// SUMF[pr] at SUM_OFF+pr*16, SUMB[pr] at SUM_OFF+(NP+pr)*16 -> one 64B line each
constexpr int SUM_WORDS = 2 * NP * 16;            // 384
constexpr int TICK_OFF = SUM_OFF + SUM_WORDS;     // ticket, own line
constexpr int ZERO_WORDS = SUM_WORDS + 16;        // sums + ticket line (400)
constexpr int MK_OFF   = TICK_OFF + 16;           // [NP][6][96] column masks (w0..2=bd_a, w3..5=bd_b)

__device__ __forceinline__ int SUMF_I(int pr) { return SUM_OFF + pr * 16; }
__device__ __forceinline__ int SUMB_I(int pr) { return SUM_OFF + (NP + pr) * 16; }
}

// K1: fully fused front end. Block = (image, 32-row band), 384 threads.
// Phase A: argmax+label once per pixel (band + halo rows) into LDS.
// Phase B: boundary flags from LDS neighbors -> global flag bytes + counts.
//          boundary = img*(5-new) > 0 <=> in-mask && (#in-bounds same-class nbrs) < 4.
// Phase C: column-mask words for this band (word index == band) + count partials.
__global__ __launch_bounds__(384) void k_front(const float* __restrict__ preds,
                                               const int* __restrict__ labels,
                                               int* __restrict__ wi) {
    int blk = blockIdx.x, j = threadIdx.x;
    int b = blk / NBANDS, w = blk - b * NBANDS;
    int y0 = w * 32;
    const float* pb = preds + (size_t)b * Cn * HWn;
    const int*   lb = labels + b * HWn;

    __shared__ unsigned char apc[34 * 96];    // argmax class, rows y0-1 .. y0+32
    __shared__ unsigned char albl[34 * 96];   // label class, same rows
    __shared__ unsigned char aflg[32 * 96];   // flag byte, band rows
    __shared__ int scnt[6];

    if (j < 6) scnt[j] = 0;

    // phase A
    for (int t = j; t < 34 * 96; t += 384) {
        int r = t / 96, x = t - r * 96;
        int y = y0 - 1 + r;
        if ((unsigned)y < 96u) {
            int p = y * Wn + x;
            float v0 = pb[p], v1 = pb[HWn + p], v2 = pb[2 * HWn + p];
            int bi = 0; float bv = v0;                 // strict > == jnp.argmax first-max
            if (v1 > bv) { bv = v1; bi = 1; }
            if (v2 > bv) { bv = v2; bi = 2; }
            apc[t]  = (unsigned char)bi;
            albl[t] = (unsigned char)lb[p];
        }
    }
    __syncthreads();

    // phase B (8 pixels/thread, exact cover of the 32x96 band)
    int cA[3] = {0, 0, 0}, cB[3] = {0, 0, 0};
#pragma unroll
    for (int k = 0; k < 8; ++k) {
        int t = j + k * 384;                   // 0..3071
        int r = t / 96, x = t - r * 96;
        int y = y0 + r, ly = r + 1;
        int pc = apc[ly * 96 + x], l = albl[ly * 96 + x];
        int ca = 0, cb = 0;
        if (y > 0)  { ca += (apc[(ly - 1) * 96 + x] == pc); cb += (albl[(ly - 1) * 96 + x] == l); }
        if (y < 95) { ca += (apc[(ly + 1) * 96 + x] == pc); cb += (albl[(ly + 1) * 96 + x] == l); }
        if (x > 0)  { ca += (apc[ly * 96 + x - 1] == pc);   cb += (albl[ly * 96 + x - 1] == l); }
        if (x < 95) { ca += (apc[ly * 96 + x + 1] == pc);   cb += (albl[ly * 96 + x + 1] == l); }
        unsigned char f = (unsigned char)(pc | (l << 2) | ((ca < 4) << 4) | ((cb < 4) << 5));
        aflg[t] = f;
        ((unsigned char*)wi)[b * HWn + y * Wn + x] = f;
        cA[0] += (pc == 0); cA[1] += (pc == 1); cA[2] += (pc == 2);
        cB[0] += (l == 0);  cB[1] += (l == 1);  cB[2] += (l == 2);
    }
    int vals[6] = {cA[0], cA[1], cA[2], cB[0], cB[1], cB[2]};
#pragma unroll
    for (int q = 0; q < 6; ++q) {
        int v = vals[q];
#pragma unroll
        for (int off = 32; off >= 1; off >>= 1) v += __shfl_xor(v, off, 64);
        if ((j & 63) == 0) atomicAdd(&scnt[q], v);     // 6 waves x 6 LDS atomics
    }
    __syncthreads();

    // phase C: this band's mask words (576 = 3 classes x {a,b} x 96 cols)
    for (int k = j; k < 576; k += 384) {
        int c = k / 192, rem = k - c * 192;
        int which = rem / 96, x = rem - which * 96;
        unsigned m = 0;
#pragma unroll
        for (int r = 0; r < 32; ++r) {
            unsigned f = aflg[r * 96 + x];
            unsigned bit = (which == 0)
                ? (unsigned)(((f & 3) == (unsigned)c) & ((f >> 4) & 1))
                : (unsigned)((((f >> 2) & 3) == (unsigned)c) & ((f >> 5) & 1));
            m |= bit << r;
        }
        int pr = b * Cn + c;
        wi[MK_OFF + pr * 576 + (which ? (w + 3) : w) * 96 + x] = (int)m;
    }
    if (j < 6) wi[CNT_OFF + blk * 8 + j] = scnt[j];    // band-partial counts
    if (blk == 0) {                 // zero K2's accumulators + ticket (stream-ordered)
        if (j < ZERO_WORDS) wi[SUM_OFF + j] = 0;
        if (j + 384 < ZERO_WORDS) wi[SUM_OFF + j + 384] = 0;
    }
}

// K2: fused EDT pass1 (bitmask nearest-set-bit) + pass2 (exact integer min G+dx^2)
// + masked sqrt sums (block-reduced, <=2 atomics/block on private cachelines)
// + last-block finalization (ticket pattern).
__global__ __launch_bounds__(384) void k_edt_sum(int* __restrict__ wi,
                                                 float* __restrict__ wf,
                                                 float* __restrict__ out) {
    int pr = blockIdx.y;
    int rb = blockIdx.x;            // 0..23 (4-row band)
    int j  = threadIdx.x;           // 0..383
    int b = pr / Cn, c = pr - b * Cn;

    __shared__ unsigned int mlds[576];   // [6][96] column mask words
    __shared__ unsigned int glds[384];   // [4][96] packed u16: lo=G_bb(label), hi=G_ba(pred)
    __shared__ float sF6[6], sB6[6];
    __shared__ int lastflag;

    for (int k = j; k < 576; k += 384)
        mlds[k] = (unsigned int)wi[MK_OFF + pr * 576 + k];
    __syncthreads();

    int r = j / 96, xp = j - r * 96;
    int y = rb * 4 + r;

    unsigned long long alo = (unsigned long long)mlds[xp]
                           | ((unsigned long long)mlds[96 + xp] << 32);
    unsigned long long ahi = mlds[192 + xp];
    unsigned long long blo = (unsigned long long)mlds[288 + xp]
                           | ((unsigned long long)mlds[384 + xp] << 32);
    unsigned long long bhi = mlds[480 + xp];

    __uint128_t Ma = ((__uint128_t)ahi << 64) | alo;   // pred boundary
    __uint128_t Mb = ((__uint128_t)bhi << 64) | blo;   // label boundary

    auto dist1d = [&](__uint128_t M) -> int {
        int du = 200, dd = 200;
        __uint128_t s = M >> y;
        if (s) {
            unsigned long long lo = (unsigned long long)s;
            du = lo ? __builtin_ctzll(lo) : 64 + __builtin_ctzll((unsigned long long)(s >> 64));
        }
        s = M << (127 - y);
        if (s) {
            unsigned long long h = (unsigned long long)(s >> 64);
            dd = h ? __builtin_clzll(h) : 64 + __builtin_clzll((unsigned long long)s);
        }
        int d = min(du, dd);
        return (d >= Hn) ? SENT : d * d;
    };
    glds[j] = (unsigned)dist1d(Mb) | ((unsigned)dist1d(Ma) << 16);
    __syncthreads();

    // pass 2 for pixel (y, xp)
    int p = y * Wn + xp;
    unsigned f = ((const unsigned char*)wi)[b * HWn + p];
    int a  = ((f & 3) == (unsigned)c);
    int bm = (((f >> 2) & 3) == (unsigned)c);
    int na = wi[CNT_OFF + (b * NBANDS + 0) * 8 + c]
           + wi[CNT_OFF + (b * NBANDS + 1) * 8 + c]
           + wi[CNT_OFF + (b * NBANDS + 2) * 8 + c];
    int nb = wi[CNT_OFF + (b * NBANDS + 0) * 8 + 3 + c]
           + wi[CNT_OFF + (b * NBANDS + 1) * 8 + 3 + c]
           + wi[CNT_OFF + (b * NBANDS + 2) * 8 + 3 + c];
    // nonempty mask <=> nonempty boundary (edge pixels have <4 in-bounds nbrs)
    bool af = a && !bm && (nb > 0);
    bool bw = bm && !a && (na > 0);

    float s = 0.0f;
    if (af || bw) {
        int sh = af ? 0 : 16;
        int md2 = 0x7fffffff;
        const unsigned int* grow = &glds[r * 96];
#pragma unroll 8
        for (int q = 0; q < Wn; ++q) {
            int gs = (grow[q] >> sh) & 0xffff;
            int dx = xp - q;
            md2 = min(md2, gs + dx * dx);
        }
        s = sqrtf((float)md2);   // integer md2 <= 18050: fp32-exact, matches reference
    }
    float vF = af ? s : 0.0f;
    float vB = bw ? s : 0.0f;
#pragma unroll
    for (int off = 32; off >= 1; off >>= 1) {
        vF += __shfl_xor(vF, off, 64);
        vB += __shfl_xor(vB, off, 64);
    }
    int wv = j >> 6;
    if ((j & 63) == 0) { sF6[wv] = vF; sB6[wv] = vB; }
    __syncthreads();
    // <=2 atomics per block, each target owns a 64B line (12+12 lines total)
    if (j == 0) {
        float t = sF6[0] + sF6[1] + sF6[2] + sF6[3] + sF6[4] + sF6[5];
        if (t != 0.0f) atomicAdd(&wf[SUMF_I(pr)], t);
    } else if (j == 64) {
        float t = sB6[0] + sB6[1] + sB6[2] + sB6[3] + sB6[4] + sB6[5];
        if (t != 0.0f) atomicAdd(&wf[SUMB_I(pr)], t);
    }

    // ticket: last of the 288 blocks finalizes the 25 outputs.
    // __syncthreads drains each wave's outstanding atomics (s_waitcnt before
    // s_barrier), so sum-atomics are at the coherence point before the ticket.
    __syncthreads();
    if (j == 0) {
        int old = atomicAdd(&wi[TICK_OFF], 1);
        lastflag = (old == NP * 24 - 1);
    }
    __syncthreads();
    if (!lastflag) return;

    __shared__ float hds[12];
    __shared__ float fld[12];
    if (j < 12) {
        int bb = j / Cn, cc = j - bb * Cn;
        int nA = wi[CNT_OFF + (bb * NBANDS + 0) * 8 + cc]
               + wi[CNT_OFF + (bb * NBANDS + 1) * 8 + cc]
               + wi[CNT_OFF + (bb * NBANDS + 2) * 8 + cc];
        int nB = wi[CNT_OFF + (bb * NBANDS + 0) * 8 + 3 + cc]
               + wi[CNT_OFF + (bb * NBANDS + 1) * 8 + 3 + cc]
               + wi[CNT_OFF + (bb * NBANDS + 2) * 8 + 3 + cc];
        float sFv = atomicAdd(&wf[SUMF_I(j)], 0.0f);   // device-coherent atomic load
        float sBv = atomicAdd(&wf[SUMB_I(j)], 0.0f);
        float h, fl = 0.0f;
        if (nA == 0) { h = (Hn + Wn) / 4.0f; fl = 1.0f; }
        else {
            h = fmaxf(sFv / fmaxf((float)nA, 1.0f), sBv / fmaxf((float)nB, 1.0f));
        }
        if (cc == 0) { h = 0.0f; fl = 0.0f; }          // IGNORE class
        hds[j] = h; fld[j] = fl;
    }
    __syncthreads();
    if (j == 0) {
        float failed[3] = {0.f, 0.f, 0.f};
        for (int q = 0; q < 12; ++q) failed[q % 3] += fld[q];
        for (int bb = 0; bb < Bn; ++bb) {
            float* row = out + bb * (Cn + 2);
            float ssum = 0.f;
            for (int cc = 0; cc < Cn; ++cc) { row[cc] = hds[bb * 3 + cc]; ssum += row[cc]; }
            row[Cn]     = ssum / (float)Cn;
            row[Cn + 1] = (hds[bb * 3] + hds[bb * 3 + 1]) / (float)(Cn - 1);
        }
        float* Fc = out + Bn * (Cn + 2);
        float fs = 0.f;
        for (int cc = 0; cc < Cn; ++cc) { Fc[cc] = failed[cc]; fs += failed[cc]; }
        Fc[Cn]     = fs / (float)Cn;
        Fc[Cn + 1] = (failed[1] + failed[2]) / (float)(Cn - 1);
    }
}

extern "C" void kernel_launch(void* const* d_in, const int* in_sizes, int n_in,
                              void* d_out, int out_size, void* d_ws, size_t ws_size,
                              hipStream_t stream) {
    const float* preds  = (const float*)d_in[0];
    const int*   labels = (const int*)d_in[1];
    float* out = (float*)d_out;
    int*   wi = (int*)d_ws;
    float* wf = (float*)d_ws;

    // K1: fused argmax + boundary + masks + counts (12 x 384)
    k_front<<<NBLK1, 384, 0, stream>>>(preds, labels, wi);
    // K2: EDT + masked sums + last-block finalize (grid 24 x 12, 384 thr)
    dim3 g2(Hn / 4, NP);
    k_edt_sum<<<g2, 384, 0, stream>>>(wi, wf, out);
}

// Round 9
// 71.545 us; speedup vs baseline: 1.0455x; 1.0455x over previous
//
#include <hip/hip_runtime.h>
#include <math.h>

namespace {
constexpr int Bn = 4, Cn = 3, Hn = 96, Wn = 96;
constexpr int HWn = Hn * Wn;          // 9216
constexpr int NP  = Bn * Cn;          // 12 (batch,class) pairs
constexpr int NBANDS = 3;             // 32-row bands; band == column-mask word index
constexpr int NCHUNK = 4;             // 24-column chunks
constexpr int BPI   = NBANDS * NCHUNK;      // 12 blocks per image
constexpr int NBLK1 = Bn * BPI;             // 48 blocks in K1
constexpr int SENT = 62500;           // "no boundary in column" d^2 (> 9025+9025)

// ws layout in 4-byte words (~71 KB total).
// flags: [B][HW] bytes at word offset 0. Byte = pc(2b) | label(2b) | bda(1b) | bdb(1b)
constexpr int FLAG_WORDS = Bn * HWn / 4;          // 9216
constexpr int CNT_OFF  = FLAG_WORDS;              // [48 blocks][8]: na[c]=slot c, nb[c]=slot 3+c
constexpr int SUM_OFF  = ((CNT_OFF + NBLK1 * 8 + 15) / 16) * 16;  // line-aligned atomics
// SUMF[pr] at SUM_OFF+pr*16, SUMB[pr] at SUM_OFF+(NP+pr)*16 -> one 64B line each
constexpr int SUM_WORDS = 2 * NP * 16;            // 384
constexpr int TICK_OFF = SUM_OFF + SUM_WORDS;     // ticket, own line
constexpr int ZERO_WORDS = SUM_WORDS + 16;        // sums + ticket line (400)
constexpr int MK_OFF   = TICK_OFF + 16;           // [NP][6][96] column masks (w0..2=bd_a, w3..5=bd_b)

__device__ __forceinline__ int SUMF_I(int pr) { return SUM_OFF + pr * 16; }
__device__ __forceinline__ int SUMB_I(int pr) { return SUM_OFF + (NP + pr) * 16; }
}

// K1: fused front end, parallelism-preserving. Block = (image, band, col-chunk):
// 32x24 tile + 1-px halo. Phase A: argmax+label once per halo pixel into LDS.
// Phase B: boundary flags from LDS neighbors -> global flag bytes + count partials.
//          boundary = img*(5-new) > 0 <=> in-mask && (#in-bounds same-class nbrs) < 4.
// Phase C: this band's column-mask words for the 24 owned columns.
__global__ __launch_bounds__(256) void k_front(const float* __restrict__ preds,
                                               const int* __restrict__ labels,
                                               int* __restrict__ wi) {
    int blk = blockIdx.x, j = threadIdx.x;
    int b = blk / BPI, rem = blk - b * BPI;
    int w = rem / NCHUNK, q = rem - w * NCHUNK;
    int y0 = w * 32, x0 = q * 24;
    const float* pb = preds + (size_t)b * Cn * HWn;
    const int*   lb = labels + b * HWn;

    __shared__ unsigned char apc[34 * 26];    // argmax class, rows y0-1..y0+32, cols x0-1..x0+24
    __shared__ unsigned char albl[34 * 26];   // label class, same window
    __shared__ unsigned char aflg[32 * 24];   // flag byte, owned tile
    __shared__ int scnt[6];

    if (j < 6) scnt[j] = 0;

    // phase A: 884 halo pixels, ~3.5 per thread, independent loads
    for (int t = j; t < 34 * 26; t += 256) {
        int r = t / 26, xl = t - r * 26;
        int y = y0 - 1 + r, x = x0 - 1 + xl;
        if ((unsigned)y < 96u && (unsigned)x < 96u) {
            int p = y * Wn + x;
            float v0 = pb[p], v1 = pb[HWn + p], v2 = pb[2 * HWn + p];
            int bi = 0; float bv = v0;                 // strict > == jnp.argmax first-max
            if (v1 > bv) { bv = v1; bi = 1; }
            if (v2 > bv) { bv = v2; bi = 2; }
            apc[t]  = (unsigned char)bi;
            albl[t] = (unsigned char)lb[p];
        }
    }
    __syncthreads();

    // phase B: 3 owned pixels per thread (768 = 3*256)
    int cA[3] = {0, 0, 0}, cB[3] = {0, 0, 0};
#pragma unroll
    for (int k = 0; k < 3; ++k) {
        int t = j + k * 256;                   // 0..767
        int r = t / 24, xl = t - r * 24;
        int y = y0 + r, x = x0 + xl;
        int li = (r + 1) * 26 + (xl + 1);
        int pc = apc[li], l = albl[li];
        int ca = 0, cb = 0;
        if (y > 0)  { ca += (apc[li - 26] == pc); cb += (albl[li - 26] == l); }
        if (y < 95) { ca += (apc[li + 26] == pc); cb += (albl[li + 26] == l); }
        if (x > 0)  { ca += (apc[li - 1] == pc);  cb += (albl[li - 1] == l); }
        if (x < 95) { ca += (apc[li + 1] == pc);  cb += (albl[li + 1] == l); }
        unsigned char f = (unsigned char)(pc | (l << 2) | ((ca < 4) << 4) | ((cb < 4) << 5));
        aflg[t] = f;
        ((unsigned char*)wi)[b * HWn + y * Wn + x] = f;
        cA[0] += (pc == 0); cA[1] += (pc == 1); cA[2] += (pc == 2);
        cB[0] += (l == 0);  cB[1] += (l == 1);  cB[2] += (l == 2);
    }
    int vals[6] = {cA[0], cA[1], cA[2], cB[0], cB[1], cB[2]};
#pragma unroll
    for (int qq = 0; qq < 6; ++qq) {
        int v = vals[qq];
#pragma unroll
        for (int off = 32; off >= 1; off >>= 1) v += __shfl_xor(v, off, 64);
        if ((j & 63) == 0) atomicAdd(&scnt[qq], v);    // 4 waves x 6 LDS atomics
    }
    __syncthreads();                                   // aflg + scnt complete

    // phase C: 144 mask words (3 classes x {a,b} x 24 cols), one per thread
    if (j < 144) {
        int c = j / 48, rem2 = j - c * 48;
        int which = rem2 / 24, xl = rem2 - which * 24;
        unsigned m = 0;
#pragma unroll
        for (int r = 0; r < 32; ++r) {
            unsigned f = aflg[r * 24 + xl];
            unsigned bit = (which == 0)
                ? (unsigned)(((f & 3) == (unsigned)c) & ((f >> 4) & 1))
                : (unsigned)((((f >> 2) & 3) == (unsigned)c) & ((f >> 5) & 1));
            m |= bit << r;
        }
        int pr = b * Cn + c;
        wi[MK_OFF + pr * 576 + (which ? (w + 3) : w) * 96 + (x0 + xl)] = (int)m;
    }
    if (j < 6) wi[CNT_OFF + blk * 8 + j] = scnt[j];    // per-block partial counts
    if (blk == 0) {                 // zero K2's accumulators + ticket (stream-ordered)
        if (j < ZERO_WORDS) wi[SUM_OFF + j] = 0;
        if (j + 256 < ZERO_WORDS) wi[SUM_OFF + j + 256] = 0;
    }
}

// K2: fused EDT pass1 (bitmask nearest-set-bit) + pass2 (exact integer min G+dx^2)
// + masked sqrt sums (block-reduced, <=2 atomics/block on private cachelines)
// + last-block finalization (ticket pattern).
__global__ __launch_bounds__(384) void k_edt_sum(int* __restrict__ wi,
                                                 float* __restrict__ wf,
                                                 float* __restrict__ out) {
    int pr = blockIdx.y;
    int rb = blockIdx.x;            // 0..23 (4-row band)
    int j  = threadIdx.x;           // 0..383
    int b = pr / Cn, c = pr - b * Cn;

    __shared__ unsigned int mlds[576];   // [6][96] column mask words
    __shared__ unsigned int glds[384];   // [4][96] packed u16: lo=G_bb(label), hi=G_ba(pred)
    __shared__ float sF6[6], sB6[6];
    __shared__ int nab[2];
    __shared__ int lastflag;

    for (int k = j; k < 576; k += 384)
        mlds[k] = (unsigned int)wi[MK_OFF + pr * 576 + k];
    if (j < 2) {                        // na (j=0) / nb (j=1): sum 12 block partials
        int s = 0;
        for (int k = 0; k < BPI; ++k)
            s += wi[CNT_OFF + (b * BPI + k) * 8 + j * 3 + c];
        nab[j] = s;
    }
    __syncthreads();

    int r = j / 96, xp = j - r * 96;
    int y = rb * 4 + r;

    unsigned long long alo = (unsigned long long)mlds[xp]
                           | ((unsigned long long)mlds[96 + xp] << 32);
    unsigned long long ahi = mlds[192 + xp];
    unsigned long long blo = (unsigned long long)mlds[288 + xp]
                           | ((unsigned long long)mlds[384 + xp] << 32);
    unsigned long long bhi = mlds[480 + xp];

    __uint128_t Ma = ((__uint128_t)ahi << 64) | alo;   // pred boundary
    __uint128_t Mb = ((__uint128_t)bhi << 64) | blo;   // label boundary

    auto dist1d = [&](__uint128_t M) -> int {
        int du = 200, dd = 200;
        __uint128_t s = M >> y;
        if (s) {
            unsigned long long lo = (unsigned long long)s;
            du = lo ? __builtin_ctzll(lo) : 64 + __builtin_ctzll((unsigned long long)(s >> 64));
        }
        s = M << (127 - y);
        if (s) {
            unsigned long long h = (unsigned long long)(s >> 64);
            dd = h ? __builtin_clzll(h) : 64 + __builtin_clzll((unsigned long long)s);
        }
        int d = min(du, dd);
        return (d >= Hn) ? SENT : d * d;
    };
    glds[j] = (unsigned)dist1d(Mb) | ((unsigned)dist1d(Ma) << 16);
    __syncthreads();

    // pass 2 for pixel (y, xp)
    int p = y * Wn + xp;
    unsigned f = ((const unsigned char*)wi)[b * HWn + p];
    int a  = ((f & 3) == (unsigned)c);
    int bm = (((f >> 2) & 3) == (unsigned)c);
    int na = nab[0], nb = nab[1];
    // nonempty mask <=> nonempty boundary (edge pixels have <4 in-bounds nbrs)
    bool af = a && !bm && (nb > 0);
    bool bw = bm && !a && (na > 0);

    float s = 0.0f;
    if (af || bw) {
        int sh = af ? 0 : 16;
        int md2 = 0x7fffffff;
        const unsigned int* grow = &glds[r * 96];
#pragma unroll 8
        for (int q = 0; q < Wn; ++q) {
            int gs = (grow[q] >> sh) & 0xffff;
            int dx = xp - q;
            md2 = min(md2, gs + dx * dx);
        }
        s = sqrtf((float)md2);   // integer md2 <= 18050: fp32-exact, matches reference
    }
    float vF = af ? s : 0.0f;
    float vB = bw ? s : 0.0f;
#pragma unroll
    for (int off = 32; off >= 1; off >>= 1) {
        vF += __shfl_xor(vF, off, 64);
        vB += __shfl_xor(vB, off, 64);
    }
    int wv = j >> 6;
    if ((j & 63) == 0) { sF6[wv] = vF; sB6[wv] = vB; }
    __syncthreads();
    // <=2 atomics per block, each target owns a 64B line (12+12 lines total)
    if (j == 0) {
        float t = sF6[0] + sF6[1] + sF6[2] + sF6[3] + sF6[4] + sF6[5];
        if (t != 0.0f) atomicAdd(&wf[SUMF_I(pr)], t);
    } else if (j == 64) {
        float t = sB6[0] + sB6[1] + sB6[2] + sB6[3] + sB6[4] + sB6[5];
        if (t != 0.0f) atomicAdd(&wf[SUMB_I(pr)], t);
    }

    // ticket: last of the 288 blocks finalizes the 25 outputs.
    // __syncthreads drains each wave's outstanding atomics (s_waitcnt before
    // s_barrier), so sum-atomics are at the coherence point before the ticket.
    __syncthreads();
    if (j == 0) {
        int old = atomicAdd(&wi[TICK_OFF], 1);
        lastflag = (old == NP * 24 - 1);
    }
    __syncthreads();
    if (!lastflag) return;

    __shared__ float hds[12];
    __shared__ float fld[12];
    if (j < 12) {
        int bb = j / Cn, cc = j - bb * Cn;
        int nA = 0, nB = 0;
        for (int k = 0; k < BPI; ++k) {
            nA += wi[CNT_OFF + (bb * BPI + k) * 8 + cc];
            nB += wi[CNT_OFF + (bb * BPI + k) * 8 + 3 + cc];
        }
        float sFv = atomicAdd(&wf[SUMF_I(j)], 0.0f);   // device-coherent atomic load
        float sBv = atomicAdd(&wf[SUMB_I(j)], 0.0f);
        float h, fl = 0.0f;
        if (nA == 0) { h = (Hn + Wn) / 4.0f; fl = 1.0f; }
        else {
            h = fmaxf(sFv / fmaxf((float)nA, 1.0f), sBv / fmaxf((float)nB, 1.0f));
        }
        if (cc == 0) { h = 0.0f; fl = 0.0f; }          // IGNORE class
        hds[j] = h; fld[j] = fl;
    }
    __syncthreads();
    if (j == 0) {
        float failed[3] = {0.f, 0.f, 0.f};
        for (int q = 0; q < 12; ++q) failed[q % 3] += fld[q];
        for (int bb = 0; bb < Bn; ++bb) {
            float* row = out + bb * (Cn + 2);
            float ssum = 0.f;
            for (int cc = 0; cc < Cn; ++cc) { row[cc] = hds[bb * 3 + cc]; ssum += row[cc]; }
            row[Cn]     = ssum / (float)Cn;
            row[Cn + 1] = (hds[bb * 3] + hds[bb * 3 + 1]) / (float)(Cn - 1);
        }
        float* Fc = out + Bn * (Cn + 2);
        float fs = 0.f;
        for (int cc = 0; cc < Cn; ++cc) { Fc[cc] = failed[cc]; fs += failed[cc]; }
        Fc[Cn]     = fs / (float)Cn;
        Fc[Cn + 1] = (failed[1] + failed[2]) / (float)(Cn - 1);
    }
}

extern "C" void kernel_launch(void* const* d_in, const int* in_sizes, int n_in,
                              void* d_out, int out_size, void* d_ws, size_t ws_size,
                              hipStream_t stream) {
    const float* preds  = (const float*)d_in[0];
    const int*   labels = (const int*)d_in[1];
    float* out = (float*)d_out;
    int*   wi = (int*)d_ws;
    float* wf = (float*)d_ws;

    // K1: fused argmax + boundary + masks + counts (48 x 256)
    k_front<<<NBLK1, 256, 0, stream>>>(preds, labels, wi);
    // K2: EDT + masked sums + last-block finalize (grid 24 x 12, 384 thr)
    dim3 g2(Hn / 4, NP);
    k_edt_sum<<<g2, 384, 0, stream>>>(wi, wf, out);
}